// Round 14
// baseline (210.174 us; speedup 1.0000x reference)
//
#include <hip/hip_runtime.h>
#include <math.h>

#define B_ 2
#define L_ 5000
#define E_ 20
#define H_ 5
#define FF_ 120
#define DEC_ 40
#define K_ 50
#define PAD_ 25
#define SCALE 0.22360679774997896f  // 1/sqrt(E)

#define NM 35                    // symmetric monomials deg<=3 in 4 vars
#define MST2 180                 // per-(b,h): 5 c-slots x 36 (35 used + pad)
#define MLAYER (B_ * H_ * MST2)  // 1800 floats per layer
#define ACH 128                  // keys per moment block
#define NCH 40                   // chunks per (b,h): 40*128 >= 5000

typedef float v2f __attribute__((ext_vector_type(2)));
__device__ __forceinline__ v2f vsplat(float x) { v2f r; r.x = x; r.y = x; return r; }

// monomial index tables; slot 4 is the constant-1 slot.
__constant__ int TD[NM] = {4, 0,1,2,3, 0,0,0,0,1,1,1,2,2,3,
                           0,0,0,0,0,0,0,0,0,0,1,1,1,1,1,1,2,2,2,3};
__constant__ int TE[NM] = {4, 4,4,4,4, 0,1,2,3,1,2,3,2,3,3,
                           0,0,0,0,1,1,1,2,2,3,1,1,1,2,2,3,2,2,3,3};
__constant__ int TF[NM] = {4, 4,4,4,4, 4,4,4,4,4,4,4,4,4,4,
                           0,1,2,3,1,2,3,2,3,3,1,2,3,2,3,3,2,3,3,3};

// plain monomials of x[4]; m[35] = 0 pad (all indices compile-time)
__device__ __forceinline__ void mono36(const float x[4], float m[36]) {
  int idx = 0;
  m[idx++] = 1.f;
#pragma unroll
  for (int d = 0; d < 4; d++) m[idx++] = x[d];
#pragma unroll
  for (int d = 0; d < 4; d++)
#pragma unroll
    for (int e = d; e < 4; e++) m[idx++] = x[d] * x[e];
#pragma unroll
  for (int d = 0; d < 4; d++)
#pragma unroll
    for (int e = d; e < 4; e++)
#pragma unroll
      for (int f = e; f < 4; f++) m[idx++] = x[d] * x[e] * x[f];
  m[35] = 0.f;
}

// exp(s) ~ 1 + s + s^2/2 + s^3/6; multiset multiplicity / n!
__device__ __forceinline__ void qcoef(float* mq) {
  const float S = 1.f / 6.f;
  mq[5]  *= 0.5f; mq[9]  *= 0.5f; mq[12] *= 0.5f; mq[14] *= 0.5f;
  mq[15] *= S;    mq[25] *= S;    mq[31] *= S;    mq[34] *= S;
  mq[16] *= 0.5f; mq[17] *= 0.5f; mq[18] *= 0.5f; mq[19] *= 0.5f;
  mq[22] *= 0.5f; mq[24] *= 0.5f; mq[26] *= 0.5f; mq[27] *= 0.5f;
  mq[28] *= 0.5f; mq[30] *= 0.5f; mq[32] *= 0.5f; mq[33] *= 0.5f;
}

// ---------------------------------------------------------------------------
// Kernel 1: conv embed + positional encoding; zeroes all 4 M buffers.
// ---------------------------------------------------------------------------
__global__ __launch_bounds__(256) void conv_pe_kernel(
    const float* __restrict__ x, const float* __restrict__ w,
    float* __restrict__ hbuf, float* __restrict__ Mall) {
  int tid = blockIdx.x * 256 + threadIdx.x;
  if (tid < 4 * MLAYER) Mall[tid] = 0.f;
  if (tid >= B_ * L_ * E_) return;
  int e = tid % E_;
  int bl = tid / E_;
  int b = bl / L_, l = bl % L_;

  const float* xr = x + b * L_;
  const float* wr = w + e * K_;
  float a0 = 0.f, a1 = 0.f;
#pragma unroll
  for (int k = 0; k < K_; k += 2) {
    int i0 = l + k - PAD_, i1 = i0 + 1;
    float x0 = (i0 >= 0 && i0 < L_) ? xr[i0] : 0.f;
    float x1 = (i1 >= 0 && i1 < L_) ? xr[i1] : 0.f;
    a0 += x0 * wr[k];
    a1 += x1 * wr[k + 1];
  }
  double expo = (e & 1) ? (double)(e + 1) / (double)E_ : (double)e / (double)E_;
  double factor = pow(10000.0, -expo);
  double arg = (double)l * factor;
  float pe = (e & 1) ? (float)cos(arg) : (float)sin(arg);
  hbuf[bl * E_ + e] = (a0 + a1) + pe;
}

// ---------------------------------------------------------------------------
// Kernel 2: moment accumulation into M[bh][c][36]. Block 0 pre-transposes W2.
// Inner loop reads float4 (ds_read_b128) — half the LDS instructions of v2f.
// ---------------------------------------------------------------------------
__global__ __launch_bounds__(192, 1) void moment_kernel(
    const float* __restrict__ hbuf,
    const float* __restrict__ Wk, const float* __restrict__ Wv,
    const float* __restrict__ W2, float* __restrict__ W2t,
    float* __restrict__ M) {
  __shared__ __align__(16) float kvs[10][ACH + 4];
  int bh = blockIdx.x / NCH;
  int chunk = blockIdx.x % NCH;
  int b = bh / H_, hh = bh % H_;

  if (blockIdx.x == 0) {
    for (int i = threadIdx.x; i < E_ * FF_; i += 192) {
      int e = i / FF_, j = i % FF_;
      W2t[j * E_ + e] = W2[i];
    }
  }

  if (threadIdx.x < ACH) {
    float wk[16], wv[16];
#pragma unroll
    for (int i = 0; i < 16; i++) { wk[i] = Wk[i]; wv[i] = Wv[i]; }
    int j = chunk * ACH + threadIdx.x;
    bool valid = j < L_;
    int jc = valid ? j : (L_ - 1);
    float4 s4 = *(const float4*)(hbuf + (b * L_ + jc) * E_ + hh * 4);
    float vm = valid ? 1.f : 0.f;
    int t = threadIdx.x;
    kvs[0][t] = wk[0] * s4.x + wk[1] * s4.y + wk[2] * s4.z + wk[3] * s4.w;
    kvs[1][t] = wk[4] * s4.x + wk[5] * s4.y + wk[6] * s4.z + wk[7] * s4.w;
    kvs[2][t] = wk[8] * s4.x + wk[9] * s4.y + wk[10] * s4.z + wk[11] * s4.w;
    kvs[3][t] = wk[12] * s4.x + wk[13] * s4.y + wk[14] * s4.z + wk[15] * s4.w;
    kvs[4][t] = 1.f;
    kvs[5][t] = (wv[0] * s4.x + wv[1] * s4.y + wv[2] * s4.z + wv[3] * s4.w) * vm;
    kvs[6][t] = (wv[4] * s4.x + wv[5] * s4.y + wv[6] * s4.z + wv[7] * s4.w) * vm;
    kvs[7][t] = (wv[8] * s4.x + wv[9] * s4.y + wv[10] * s4.z + wv[11] * s4.w) * vm;
    kvs[8][t] = (wv[12] * s4.x + wv[13] * s4.y + wv[14] * s4.z + wv[15] * s4.w) * vm;
    kvs[9][t] = vm;
  }
  __syncthreads();

  int t = threadIdx.x;
  if (t >= NM * 5) return;
  int m = t / 5, c = t % 5;
  int sd = TD[m], se = TE[m], sf = TF[m], sv = 5 + c;
  float a0 = 0.f, a1 = 0.f, a2 = 0.f, a3 = 0.f;
#pragma unroll 2
  for (int j = 0; j < ACH; j += 4) {
    float4 a = *(const float4*)&kvs[sd][j];
    float4 bq = *(const float4*)&kvs[se][j];
    float4 cq = *(const float4*)&kvs[sf][j];
    float4 vv = *(const float4*)&kvs[sv][j];
    a0 += a.x * bq.x * cq.x * vv.x;
    a1 += a.y * bq.y * cq.y * vv.y;
    a2 += a.z * bq.z * cq.z * vv.z;
    a3 += a.w * bq.w * cq.w * vv.w;
  }
  atomicAdd(&M[bh * MST2 + c * 36 + m], (a0 + a1) + (a2 + a3));
}

// ---------------------------------------------------------------------------
// Kernel 3: fused layer — 16-part split (2504 waves = 2.4/SIMD), no weight
// staging (all weight/moment reads are vector global loads, L1-resident).
// LDS only for cross-part hand-offs.
// grid (313, B_); block 256 = 16 pos x 16 parts.
// Splits: Wc rows {2x4,1x12}; FFN rows {8x8,7x8}; dec d1/d2 {3x8,2x8},
// d3 {2x4,1x12}.
// ---------------------------------------------------------------------------
#define DOT20G(res, W, row, vec)                                     \
  {                                                                  \
    const float4* Wr = (const float4*)((W) + (row) * 20);            \
    float c0 = 0.f, c1 = 0.f, c2 = 0.f, c3 = 0.f;                    \
    _Pragma("unroll") for (int g5 = 0; g5 < 5; g5++) {               \
      float4 w4 = Wr[g5];                                            \
      c0 += w4.x * vec[g5 * 4 + 0];                                  \
      c1 += w4.y * vec[g5 * 4 + 1];                                  \
      c2 += w4.z * vec[g5 * 4 + 2];                                  \
      c3 += w4.w * vec[g5 * 4 + 3];                                  \
    }                                                                \
    res += (c0 + c1) + (c2 + c3);                                    \
  }

#define DOT40G(res, W, row, vec)                                     \
  {                                                                  \
    const float4* Wr = (const float4*)((W) + (row) * 40);            \
    float c0 = 0.f, c1 = 0.f, c2 = 0.f, c3 = 0.f;                    \
    _Pragma("unroll") for (int g5 = 0; g5 < 10; g5++) {              \
      float4 w4 = Wr[g5];                                            \
      c0 += w4.x * vec[g5 * 4 + 0];                                  \
      c1 += w4.y * vec[g5 * 4 + 1];                                  \
      c2 += w4.z * vec[g5 * 4 + 2];                                  \
      c3 += w4.w * vec[g5 * 4 + 3];                                  \
    }                                                                \
    res += (c0 + c1) + (c2 + c3);                                    \
  }

template <int LAST>
__global__ __launch_bounds__(256) void fused_kernel(
    const float* __restrict__ M, const float* __restrict__ Wq,
    const float* __restrict__ Wc, const float* __restrict__ bc,
    const float* __restrict__ lnAg, const float* __restrict__ lnAb,
    const float* __restrict__ W1, const float* __restrict__ b1,
    const float* __restrict__ W2t, const float* __restrict__ b2,
    const float* __restrict__ lnBg, const float* __restrict__ lnBb,
    float* __restrict__ hbuf,
    const float* __restrict__ f1w, const float* __restrict__ f1b,
    const float* __restrict__ f2w, const float* __restrict__ f2b,
    const float* __restrict__ f3w, const float* __restrict__ f3b,
    const float* __restrict__ f4w, const float* __restrict__ f4b,
    float* __restrict__ out) {
  __shared__ __align__(16) float4 so4[16][7];   // [p16][head], pad->2-way
  __shared__ __align__(16) float stv[16 * 20];  // [p16][20]
  __shared__ __align__(16) float sc[256 * 20];  // [tid][20]; dec: p16*101

  int tid = threadIdx.x;
  int b = blockIdx.y;
  int p16 = tid & 15;
  int part = tid >> 4;  // 0..15
  int l = blockIdx.x * 16 + p16;
  bool act = l < L_;
  int lc = act ? l : L_ - 1;
  int pos = b * L_ + lc;

  // residual vector (constant-indexed only -> stays in VGPRs)
  float hv[E_];
#pragma unroll
  for (int e4 = 0; e4 < 5; e4++) {
    float4 h4 = *(const float4*)(hbuf + pos * E_ + e4 * 4);
    hv[e4 * 4 + 0] = h4.x; hv[e4 * 4 + 1] = h4.y;
    hv[e4 * 4 + 2] = h4.z; hv[e4 * 4 + 3] = h4.w;
  }

  // ---- A: attention eval, head = part (parts 5-15 idle) ----
  if (part < H_) {
    float4 qsrc = *(const float4*)(hbuf + pos * E_ + part * 4);
    float q[4];
#pragma unroll
    for (int d = 0; d < 4; d++) {
      q[d] = (Wq[d * 4 + 0] * qsrc.x + Wq[d * 4 + 1] * qsrc.y +
              Wq[d * 4 + 2] * qsrc.z + Wq[d * 4 + 3] * qsrc.w) *
             SCALE;
    }
    float mq[36];
    mono36(q, mq);
    qcoef(mq);
    const float* Mb = M + (b * H_ + part) * MST2;
    float oc[5];
#pragma unroll
    for (int c = 0; c < 5; c++) {
      const float4* Mr = (const float4*)(Mb + c * 36);
      float a0 = 0.f, a1 = 0.f, a2 = 0.f, a3 = 0.f;
#pragma unroll
      for (int g = 0; g < 9; g++) {
        float4 w4 = Mr[g];
        a0 += w4.x * mq[g * 4 + 0];
        a1 += w4.y * mq[g * 4 + 1];
        a2 += w4.z * mq[g * 4 + 2];
        a3 += w4.w * mq[g * 4 + 3];
      }
      oc[c] = (a0 + a1) + (a2 + a3);
    }
    float inv = 1.f / oc[4];
    so4[p16][part] =
        make_float4(oc[0] * inv, oc[1] * inv, oc[2] * inv, oc[3] * inv);
  }
  __syncthreads();

  // ---- B: Wc rows per part + bias -> stv (residual added in C) ----
  float o[E_];
#pragma unroll
  for (int hh = 0; hh < H_; hh++) {
    float4 o4 = so4[p16][hh];
    o[hh * 4 + 0] = o4.x; o[hh * 4 + 1] = o4.y;
    o[hh * 4 + 2] = o4.z; o[hh * 4 + 3] = o4.w;
  }
  {
    int r0 = (part < 4) ? part * 2 : 8 + (part - 4);
    int nr = (part < 4) ? 2 : 1;
    for (int r = 0; r < nr; r++) {
      int row = r0 + r;
      float acc = bc[row];
      DOT20G(acc, Wc, row, o);
      stv[p16 * 20 + row] = acc;
    }
  }
  __syncthreads();

  // ---- C: add residual (constant idx), LN_A (redundant per thread) ----
  float tv[E_];
#pragma unroll
  for (int e4 = 0; e4 < 5; e4++) {
    float4 t4 = *(const float4*)(stv + p16 * 20 + e4 * 4);
    tv[e4 * 4 + 0] = t4.x + hv[e4 * 4 + 0];
    tv[e4 * 4 + 1] = t4.y + hv[e4 * 4 + 1];
    tv[e4 * 4 + 2] = t4.z + hv[e4 * 4 + 2];
    tv[e4 * 4 + 3] = t4.w + hv[e4 * 4 + 3];
  }
  float mu = 0.f;
#pragma unroll
  for (int e = 0; e < E_; e++) mu += tv[e];
  mu *= (1.f / E_);
  float var = 0.f;
#pragma unroll
  for (int e = 0; e < E_; e++) { float d = tv[e] - mu; var += d * d; }
  var *= (1.f / E_);
  float rs = rsqrtf(var + 1e-5f);
  float h1[E_];
#pragma unroll
  for (int e = 0; e < E_; e++) h1[e] = (tv[e] - mu) * rs * lnAg[e] + lnAb[e];

  // ---- D: FFN, {8 or 7} rows per part ----
  float g2p[E_];
#pragma unroll
  for (int e = 0; e < E_; e++) g2p[e] = 0.f;
  {
    int jf0 = (part < 8) ? part * 8 : 64 + (part - 8) * 7;
    int nj = (part < 8) ? 8 : 7;
    for (int jj = 0; jj < nj; jj++) {
      int j = jf0 + jj;
      float f = b1[j];
      DOT20G(f, W1, j, h1);
      f = fmaxf(f, 0.f);
      const float4* Wr = (const float4*)(W2t + j * 20);
#pragma unroll
      for (int g = 0; g < 5; g++) {
        float4 w4 = Wr[g];
        g2p[g * 4 + 0] += w4.x * f;
        g2p[g * 4 + 1] += w4.y * f;
        g2p[g * 4 + 2] += w4.z * f;
        g2p[g * 4 + 3] += w4.w * f;
      }
    }
  }
  float4* scw = (float4*)(sc + tid * 20);
#pragma unroll
  for (int g = 0; g < 5; g++)
    scw[g] = make_float4(g2p[g * 4], g2p[g * 4 + 1], g2p[g * 4 + 2],
                         g2p[g * 4 + 3]);
  __syncthreads();

  // ---- E: reduce 16 partials + b2 + residual(h1), LN_B ----
  float g2[E_];
#pragma unroll
  for (int e = 0; e < E_; e++) g2[e] = b2[e] + h1[e];
#pragma unroll
  for (int pp = 0; pp < 16; pp++) {
    const float4* r = (const float4*)(sc + (pp * 16 + p16) * 20);
#pragma unroll
    for (int g = 0; g < 5; g++) {
      float4 v4 = r[g];
      g2[g * 4 + 0] += v4.x; g2[g * 4 + 1] += v4.y;
      g2[g * 4 + 2] += v4.z; g2[g * 4 + 3] += v4.w;
    }
  }
  float mu2 = 0.f;
#pragma unroll
  for (int e = 0; e < E_; e++) mu2 += g2[e];
  mu2 *= (1.f / E_);
  float var2 = 0.f;
#pragma unroll
  for (int e = 0; e < E_; e++) { float d = g2[e] - mu2; var2 += d * d; }
  var2 *= (1.f / E_);
  float rs2 = rsqrtf(var2 + 1e-5f);
  float hn[E_];
#pragma unroll
  for (int e = 0; e < E_; e++) hn[e] = (g2[e] - mu2) * rs2 * lnBg[e] + lnBb[e];

  if (!LAST) {
    if (act && part == 0) {
#pragma unroll
      for (int e4 = 0; e4 < 5; e4++) {
        *(float4*)(hbuf + pos * E_ + e4 * 4) =
            make_float4(hn[e4 * 4], hn[e4 * 4 + 1], hn[e4 * 4 + 2],
                        hn[e4 * 4 + 3]);
      }
    }
  } else {
    __syncthreads();  // reduce reads done before reusing sc
    // d1: {3 or 2} rows per part
    {
      int jd0 = (part < 8) ? part * 3 : 24 + (part - 8) * 2;
      int nd = (part < 8) ? 3 : 2;
      for (int j = 0; j < nd; j++) {
        int jj = jd0 + j;
        float a = f1b[jj];
        DOT20G(a, f1w, jj, hn);
        sc[p16 * 101 + jj] = fmaxf(a, 0.f);
      }
    }
    __syncthreads();
    float d1[DEC_];
#pragma unroll
    for (int k = 0; k < DEC_; k++) d1[k] = sc[p16 * 101 + k];
    {
      int jd0 = (part < 8) ? part * 3 : 24 + (part - 8) * 2;
      int nd = (part < 8) ? 3 : 2;
      for (int j = 0; j < nd; j++) {
        int jj = jd0 + j;
        float a = f2b[jj];
        DOT40G(a, f2w, jj, d1);
        sc[p16 * 101 + 40 + jj] = fmaxf(a, 0.f);
      }
    }
    __syncthreads();
    float d2[DEC_];
#pragma unroll
    for (int k = 0; k < DEC_; k++) d2[k] = sc[p16 * 101 + 40 + k];
    {
      int e0 = (part < 4) ? part * 2 : 8 + (part - 4);
      int ne = (part < 4) ? 2 : 1;
      for (int j = 0; j < ne; j++) {
        int ee = e0 + j;
        float a = f3b[ee];
        DOT40G(a, f3w, ee, d2);
        sc[p16 * 101 + 80 + ee] = fmaxf(a, 0.f);
      }
    }
    __syncthreads();
    if (act && part == 0) {
      float z = f4b[0];
      const float* dv = sc + p16 * 101 + 80;
      DOT20G(z, f4w, 0, dv);
      out[pos] = 1.f / (1.f + __expf(-z));
    }
  }
}

// ---------------------------------------------------------------------------
extern "C" void kernel_launch(void* const* d_in, const int* in_sizes, int n_in,
                              void* d_out, int out_size, void* d_ws,
                              size_t ws_size, hipStream_t stream) {
  const float* x    = (const float*)d_in[0];
  const float* cw   = (const float*)d_in[1];
  const float* Wv   = (const float*)d_in[2];
  const float* Wk   = (const float*)d_in[3];
  const float* Wq   = (const float*)d_in[4];
  const float* Wc   = (const float*)d_in[5];
  const float* bc   = (const float*)d_in[6];
  const float* lnAg = (const float*)d_in[7];
  const float* lnAb = (const float*)d_in[8];
  const float* W1   = (const float*)d_in[9];
  const float* b1   = (const float*)d_in[10];
  const float* W2   = (const float*)d_in[11];
  const float* b2   = (const float*)d_in[12];
  const float* lnBg = (const float*)d_in[13];
  const float* lnBb = (const float*)d_in[14];
  const float* f1w  = (const float*)d_in[15];
  const float* f1b  = (const float*)d_in[16];
  const float* f2w  = (const float*)d_in[17];
  const float* f2b  = (const float*)d_in[18];
  const float* f3w  = (const float*)d_in[19];
  const float* f3b  = (const float*)d_in[20];
  const float* f4w  = (const float*)d_in[21];
  const float* f4b  = (const float*)d_in[22];
  float* out = (float*)d_out;

  // ws floats: h 200000 | Mall 4*1800 | W2t 2400
  float* ws = (float*)d_ws;
  float* h = ws;
  float* Mall = ws + 200000;
  float* W2t = Mall + 4 * MLAYER;

  conv_pe_kernel<<<(B_ * L_ * E_ + 255) / 256, 256, 0, stream>>>(x, cw, h, Mall);

  for (int i = 0; i < 4; i++) {
    moment_kernel<<<B_ * H_ * NCH, 192, 0, stream>>>(
        h, Wk + i * 16, Wv + i * 16, W2 + i * 2400, W2t, Mall + i * MLAYER);
    dim3 grid((L_ + 15) / 16, B_);
    if (i < 3) {
      fused_kernel<0><<<grid, 256, 0, stream>>>(
          Mall + i * MLAYER, Wq + i * 16, Wc + i * 400, bc + i * 20,
          lnAg + i * 20, lnAb + i * 20, W1 + i * 2400, b1 + i * 120,
          W2t, b2 + i * 20, lnBg + i * 20, lnBb + i * 20, h,
          f1w, f1b, f2w, f2b, f3w, f3b, f4w, f4b, out);
    } else {
      fused_kernel<1><<<grid, 256, 0, stream>>>(
          Mall + i * MLAYER, Wq + i * 16, Wc + i * 400, bc + i * 20,
          lnAg + i * 20, lnAb + i * 20, W1 + i * 2400, b1 + i * 120,
          W2t, b2 + i * 20, lnBg + i * 20, lnBb + i * 20, h,
          f1w, f1b, f2w, f2b, f3w, f3b, f4w, f4b, out);
    }
  }
}

// Round 16
// 196.088 us; speedup vs baseline: 1.0718x; 1.0718x over previous
//
#include <hip/hip_runtime.h>
#include <math.h>

#define B_ 2
#define L_ 5000
#define E_ 20
#define H_ 5
#define FF_ 120
#define DEC_ 40
#define K_ 50
#define PAD_ 25
#define SCALE 0.22360679774997896f  // 1/sqrt(E)

#define NM 35                    // symmetric monomials deg<=3 in 4 vars
#define MST2 180                 // per-(b,h): 5 c-slots x 36 (35 used + pad)
#define MLAYER (B_ * H_ * MST2)  // 1800 floats per layer
#define ACH 128                  // keys per moment block
#define NCH 40                   // chunks per (b,h): 40*128 >= 5000

typedef float v2f __attribute__((ext_vector_type(2)));
__device__ __forceinline__ v2f vsplat(float x) { v2f r; r.x = x; r.y = x; return r; }

// monomial index tables; slot 4 is the constant-1 slot.
__constant__ int TD[NM] = {4, 0,1,2,3, 0,0,0,0,1,1,1,2,2,3,
                           0,0,0,0,0,0,0,0,0,0,1,1,1,1,1,1,2,2,2,3};
__constant__ int TE[NM] = {4, 4,4,4,4, 0,1,2,3,1,2,3,2,3,3,
                           0,0,0,0,1,1,1,2,2,3,1,1,1,2,2,3,2,2,3,3};
__constant__ int TF[NM] = {4, 4,4,4,4, 4,4,4,4,4,4,4,4,4,4,
                           0,1,2,3,1,2,3,2,3,3,1,2,3,2,3,3,2,3,3,3};

// plain monomials of x[4]; m[35] = 0 pad (all indices compile-time)
__device__ __forceinline__ void mono36(const float x[4], float m[36]) {
  int idx = 0;
  m[idx++] = 1.f;
#pragma unroll
  for (int d = 0; d < 4; d++) m[idx++] = x[d];
#pragma unroll
  for (int d = 0; d < 4; d++)
#pragma unroll
    for (int e = d; e < 4; e++) m[idx++] = x[d] * x[e];
#pragma unroll
  for (int d = 0; d < 4; d++)
#pragma unroll
    for (int e = d; e < 4; e++)
#pragma unroll
      for (int f = e; f < 4; f++) m[idx++] = x[d] * x[e] * x[f];
  m[35] = 0.f;
}

// exp(s) ~ 1 + s + s^2/2 + s^3/6; multiset multiplicity / n!
__device__ __forceinline__ void qcoef(float* mq) {
  const float S = 1.f / 6.f;
  mq[5]  *= 0.5f; mq[9]  *= 0.5f; mq[12] *= 0.5f; mq[14] *= 0.5f;
  mq[15] *= S;    mq[25] *= S;    mq[31] *= S;    mq[34] *= S;
  mq[16] *= 0.5f; mq[17] *= 0.5f; mq[18] *= 0.5f; mq[19] *= 0.5f;
  mq[22] *= 0.5f; mq[24] *= 0.5f; mq[26] *= 0.5f; mq[27] *= 0.5f;
  mq[28] *= 0.5f; mq[30] *= 0.5f; mq[32] *= 0.5f; mq[33] *= 0.5f;
}

// ---------------------------------------------------------------------------
// Kernel 1: conv embed + positional encoding; zeroes all 4 M buffers.
// ---------------------------------------------------------------------------
__global__ __launch_bounds__(256) void conv_pe_kernel(
    const float* __restrict__ x, const float* __restrict__ w,
    float* __restrict__ hbuf, float* __restrict__ Mall) {
  int tid = blockIdx.x * 256 + threadIdx.x;
  if (tid < 4 * MLAYER) Mall[tid] = 0.f;
  if (tid >= B_ * L_ * E_) return;
  int e = tid % E_;
  int bl = tid / E_;
  int b = bl / L_, l = bl % L_;

  const float* xr = x + b * L_;
  const float* wr = w + e * K_;
  float a0 = 0.f, a1 = 0.f;
#pragma unroll
  for (int k = 0; k < K_; k += 2) {
    int i0 = l + k - PAD_, i1 = i0 + 1;
    float x0 = (i0 >= 0 && i0 < L_) ? xr[i0] : 0.f;
    float x1 = (i1 >= 0 && i1 < L_) ? xr[i1] : 0.f;
    a0 += x0 * wr[k];
    a1 += x1 * wr[k + 1];
  }
  double expo = (e & 1) ? (double)(e + 1) / (double)E_ : (double)e / (double)E_;
  double factor = pow(10000.0, -expo);
  double arg = (double)l * factor;
  float pe = (e & 1) ? (float)cos(arg) : (float)sin(arg);
  hbuf[bl * E_ + e] = (a0 + a1) + pe;
}

// ---------------------------------------------------------------------------
// Kernel 2: moment accumulation into M[bh][c][36]. Block 0 pre-transposes W2.
// ---------------------------------------------------------------------------
__global__ __launch_bounds__(192, 1) void moment_kernel(
    const float* __restrict__ hbuf,
    const float* __restrict__ Wk, const float* __restrict__ Wv,
    const float* __restrict__ W2, float* __restrict__ W2t,
    float* __restrict__ M) {
  __shared__ __align__(16) float kvs[10][ACH + 2];
  int bh = blockIdx.x / NCH;
  int chunk = blockIdx.x % NCH;
  int b = bh / H_, hh = bh % H_;

  if (blockIdx.x == 0) {
    for (int i = threadIdx.x; i < E_ * FF_; i += 192) {
      int e = i / FF_, j = i % FF_;
      W2t[j * E_ + e] = W2[i];
    }
  }

  if (threadIdx.x < ACH) {
    float wk[16], wv[16];
#pragma unroll
    for (int i = 0; i < 16; i++) { wk[i] = Wk[i]; wv[i] = Wv[i]; }
    int j = chunk * ACH + threadIdx.x;
    bool valid = j < L_;
    int jc = valid ? j : (L_ - 1);
    float4 s4 = *(const float4*)(hbuf + (b * L_ + jc) * E_ + hh * 4);
    float vm = valid ? 1.f : 0.f;
    int t = threadIdx.x;
    kvs[0][t] = wk[0] * s4.x + wk[1] * s4.y + wk[2] * s4.z + wk[3] * s4.w;
    kvs[1][t] = wk[4] * s4.x + wk[5] * s4.y + wk[6] * s4.z + wk[7] * s4.w;
    kvs[2][t] = wk[8] * s4.x + wk[9] * s4.y + wk[10] * s4.z + wk[11] * s4.w;
    kvs[3][t] = wk[12] * s4.x + wk[13] * s4.y + wk[14] * s4.z + wk[15] * s4.w;
    kvs[4][t] = 1.f;
    kvs[5][t] = (wv[0] * s4.x + wv[1] * s4.y + wv[2] * s4.z + wv[3] * s4.w) * vm;
    kvs[6][t] = (wv[4] * s4.x + wv[5] * s4.y + wv[6] * s4.z + wv[7] * s4.w) * vm;
    kvs[7][t] = (wv[8] * s4.x + wv[9] * s4.y + wv[10] * s4.z + wv[11] * s4.w) * vm;
    kvs[8][t] = (wv[12] * s4.x + wv[13] * s4.y + wv[14] * s4.z + wv[15] * s4.w) * vm;
    kvs[9][t] = vm;
  }
  __syncthreads();

  int t = threadIdx.x;
  if (t >= NM * 5) return;
  int m = t / 5, c = t % 5;
  int sd = TD[m], se = TE[m], sf = TF[m], sv = 5 + c;
  v2f acc = vsplat(0.f);
#pragma unroll 4
  for (int j = 0; j < ACH; j += 2) {
    v2f a = *(const v2f*)&kvs[sd][j];
    v2f bq = *(const v2f*)&kvs[se][j];
    v2f cq = *(const v2f*)&kvs[sf][j];
    v2f vv = *(const v2f*)&kvs[sv][j];
    acc += a * bq * cq * vv;
  }
  atomicAdd(&M[bh * MST2 + c * 36 + m], acc.x + acc.y);
}

// ---------------------------------------------------------------------------
// Kernel 3: fused layer — NO LDS weight staging. All weight / moment /
// decoder reads are vector global loads (few distinct addresses per wave,
// L1-resident: whole per-layer weight set ~26KB < 32KB L1, vmcnt-pipelined).
// LDS holds only the cross-part hand-off buffers (so4/stv/sc ~ 13KB) ->
// 3 barriers instead of staging + 6.
// grid (313, B_); block 128 = 16 pos x 8 parts.
// ---------------------------------------------------------------------------
#define DOT20G(res, W, row, vec)                                     \
  {                                                                  \
    const float4* Wr = (const float4*)((W) + (row) * 20);            \
    float c0 = 0.f, c1 = 0.f, c2 = 0.f, c3 = 0.f;                    \
    _Pragma("unroll") for (int g5 = 0; g5 < 5; g5++) {               \
      float4 w4 = Wr[g5];                                            \
      c0 += w4.x * vec[g5 * 4 + 0];                                  \
      c1 += w4.y * vec[g5 * 4 + 1];                                  \
      c2 += w4.z * vec[g5 * 4 + 2];                                  \
      c3 += w4.w * vec[g5 * 4 + 3];                                  \
    }                                                                \
    res += (c0 + c1) + (c2 + c3);                                    \
  }

#define DOT40G(res, W, row, vec)                                     \
  {                                                                  \
    const float4* Wr = (const float4*)((W) + (row) * 40);            \
    float c0 = 0.f, c1 = 0.f, c2 = 0.f, c3 = 0.f;                    \
    _Pragma("unroll") for (int g5 = 0; g5 < 10; g5++) {              \
      float4 w4 = Wr[g5];                                            \
      c0 += w4.x * vec[g5 * 4 + 0];                                  \
      c1 += w4.y * vec[g5 * 4 + 1];                                  \
      c2 += w4.z * vec[g5 * 4 + 2];                                  \
      c3 += w4.w * vec[g5 * 4 + 3];                                  \
    }                                                                \
    res += (c0 + c1) + (c2 + c3);                                    \
  }

template <int LAST>
__global__ __launch_bounds__(128) void fused_kernel(
    const float* __restrict__ M, const float* __restrict__ Wq,
    const float* __restrict__ Wc, const float* __restrict__ bc,
    const float* __restrict__ lnAg, const float* __restrict__ lnAb,
    const float* __restrict__ W1, const float* __restrict__ b1,
    const float* __restrict__ W2t, const float* __restrict__ b2,
    const float* __restrict__ lnBg, const float* __restrict__ lnBb,
    float* __restrict__ hbuf,
    const float* __restrict__ f1w, const float* __restrict__ f1b,
    const float* __restrict__ f2w, const float* __restrict__ f2b,
    const float* __restrict__ f3w, const float* __restrict__ f3b,
    const float* __restrict__ f4w, const float* __restrict__ f4b,
    float* __restrict__ out) {
  __shared__ __align__(16) float4 so4[16][7];   // [p16][head], pad->2-way
  __shared__ __align__(16) float stv[16 * 20];  // [p16][20]
  __shared__ __align__(16) float sc[128 * 20];  // [tid][20]; dec: p16*101

  int tid = threadIdx.x;
  int b = blockIdx.y;
  int p16 = tid & 15;
  int part = tid >> 4;  // 0..7
  int l = blockIdx.x * 16 + p16;
  bool act = l < L_;
  int lc = act ? l : L_ - 1;
  int pos = b * L_ + lc;

  // residual vector (constant-indexed only -> stays in VGPRs)
  float hv[E_];
#pragma unroll
  for (int e4 = 0; e4 < 5; e4++) {
    float4 h4 = *(const float4*)(hbuf + pos * E_ + e4 * 4);
    hv[e4 * 4 + 0] = h4.x; hv[e4 * 4 + 1] = h4.y;
    hv[e4 * 4 + 2] = h4.z; hv[e4 * 4 + 3] = h4.w;
  }

  // ---- A: attention eval, head = part (parts 5-7 idle) ----
  if (part < H_) {
    float4 qsrc = *(const float4*)(hbuf + pos * E_ + part * 4);
    float q[4];
#pragma unroll
    for (int d = 0; d < 4; d++) {
      q[d] = (Wq[d * 4 + 0] * qsrc.x + Wq[d * 4 + 1] * qsrc.y +
              Wq[d * 4 + 2] * qsrc.z + Wq[d * 4 + 3] * qsrc.w) *
             SCALE;
    }
    float mq[36];
    mono36(q, mq);
    qcoef(mq);
    const float* Mb = M + (b * H_ + part) * MST2;
    float oc[5];
#pragma unroll
    for (int c = 0; c < 5; c++) {
      const float4* Mr = (const float4*)(Mb + c * 36);
      float a0 = 0.f, a1 = 0.f, a2 = 0.f, a3 = 0.f;
#pragma unroll
      for (int g = 0; g < 9; g++) {
        float4 w4 = Mr[g];
        a0 += w4.x * mq[g * 4 + 0];
        a1 += w4.y * mq[g * 4 + 1];
        a2 += w4.z * mq[g * 4 + 2];
        a3 += w4.w * mq[g * 4 + 3];
      }
      oc[c] = (a0 + a1) + (a2 + a3);
    }
    float inv = 1.f / oc[4];
    so4[p16][part] =
        make_float4(oc[0] * inv, oc[1] * inv, oc[2] * inv, oc[3] * inv);
  }
  __syncthreads();

  // ---- B: Wc rows per part + bias -> stv (residual added in C) ----
  float o[E_];
#pragma unroll
  for (int hh = 0; hh < H_; hh++) {
    float4 o4 = so4[p16][hh];
    o[hh * 4 + 0] = o4.x; o[hh * 4 + 1] = o4.y;
    o[hh * 4 + 2] = o4.z; o[hh * 4 + 3] = o4.w;
  }
  int r0 = (part < 4) ? part * 3 : 12 + (part - 4) * 2;
  int nr = (part < 4) ? 3 : 2;
  for (int r = 0; r < nr; r++) {
    int row = r0 + r;
    float acc = bc[row];
    DOT20G(acc, Wc, row, o);
    stv[p16 * 20 + row] = acc;
  }
  __syncthreads();

  // ---- C: add residual (constant idx), LN_A (redundant per thread) ----
  float tv[E_];
#pragma unroll
  for (int e4 = 0; e4 < 5; e4++) {
    float4 t4 = *(const float4*)(stv + p16 * 20 + e4 * 4);
    tv[e4 * 4 + 0] = t4.x + hv[e4 * 4 + 0];
    tv[e4 * 4 + 1] = t4.y + hv[e4 * 4 + 1];
    tv[e4 * 4 + 2] = t4.z + hv[e4 * 4 + 2];
    tv[e4 * 4 + 3] = t4.w + hv[e4 * 4 + 3];
  }
  float mu = 0.f;
#pragma unroll
  for (int e = 0; e < E_; e++) mu += tv[e];
  mu *= (1.f / E_);
  float var = 0.f;
#pragma unroll
  for (int e = 0; e < E_; e++) { float d = tv[e] - mu; var += d * d; }
  var *= (1.f / E_);
  float rs = rsqrtf(var + 1e-5f);
  float h1[E_];
#pragma unroll
  for (int e = 0; e < E_; e++) h1[e] = (tv[e] - mu) * rs * lnAg[e] + lnAb[e];

  // ---- D: FFN, 15 rows per part ----
  float g2p[E_];
#pragma unroll
  for (int e = 0; e < E_; e++) g2p[e] = 0.f;
  int jf0 = part * (FF_ / 8);
#pragma unroll
  for (int jj = 0; jj < FF_ / 8; jj++) {
    int j = jf0 + jj;
    float f = b1[j];
    DOT20G(f, W1, j, h1);
    f = fmaxf(f, 0.f);
    const float4* Wr = (const float4*)(W2t + j * 20);
#pragma unroll
    for (int g = 0; g < 5; g++) {
      float4 w4 = Wr[g];
      g2p[g * 4 + 0] += w4.x * f;
      g2p[g * 4 + 1] += w4.y * f;
      g2p[g * 4 + 2] += w4.z * f;
      g2p[g * 4 + 3] += w4.w * f;
    }
  }
  float4* scw = (float4*)(sc + tid * 20);
#pragma unroll
  for (int g = 0; g < 5; g++)
    scw[g] = make_float4(g2p[g * 4], g2p[g * 4 + 1], g2p[g * 4 + 2],
                         g2p[g * 4 + 3]);
  __syncthreads();

  // ---- E: reduce 8 partials + b2 + residual(h1), LN_B ----
  float g2[E_];
#pragma unroll
  for (int e = 0; e < E_; e++) g2[e] = b2[e] + h1[e];
#pragma unroll
  for (int pp = 0; pp < 8; pp++) {
    const float4* r = (const float4*)(sc + (pp * 16 + p16) * 20);
#pragma unroll
    for (int g = 0; g < 5; g++) {
      float4 v4 = r[g];
      g2[g * 4 + 0] += v4.x; g2[g * 4 + 1] += v4.y;
      g2[g * 4 + 2] += v4.z; g2[g * 4 + 3] += v4.w;
    }
  }
  float mu2 = 0.f;
#pragma unroll
  for (int e = 0; e < E_; e++) mu2 += g2[e];
  mu2 *= (1.f / E_);
  float var2 = 0.f;
#pragma unroll
  for (int e = 0; e < E_; e++) { float d = g2[e] - mu2; var2 += d * d; }
  var2 *= (1.f / E_);
  float rs2 = rsqrtf(var2 + 1e-5f);
  float hn[E_];
#pragma unroll
  for (int e = 0; e < E_; e++) hn[e] = (g2[e] - mu2) * rs2 * lnBg[e] + lnBb[e];

  if (!LAST) {
    if (act && part == 0) {
#pragma unroll
      for (int e4 = 0; e4 < 5; e4++) {
        *(float4*)(hbuf + pos * E_ + e4 * 4) =
            make_float4(hn[e4 * 4], hn[e4 * 4 + 1], hn[e4 * 4 + 2],
                        hn[e4 * 4 + 3]);
      }
    }
  } else {
    __syncthreads();  // reduce reads done before reusing sc
    // d1: 5 rows per part (f1w global)
#pragma unroll
    for (int j = 0; j < DEC_ / 8; j++) {
      int jj = part * (DEC_ / 8) + j;
      float a = f1b[jj];
      DOT20G(a, f1w, jj, hn);
      sc[p16 * 101 + jj] = fmaxf(a, 0.f);
    }
    __syncthreads();
    float d1[DEC_];
#pragma unroll
    for (int k = 0; k < DEC_; k++) d1[k] = sc[p16 * 101 + k];
#pragma unroll
    for (int j = 0; j < DEC_ / 8; j++) {
      int jj = part * (DEC_ / 8) + j;
      float a = f2b[jj];
      DOT40G(a, f2w, jj, d1);
      sc[p16 * 101 + 40 + jj] = fmaxf(a, 0.f);
    }
    __syncthreads();
    float d2[DEC_];
#pragma unroll
    for (int k = 0; k < DEC_; k++) d2[k] = sc[p16 * 101 + 40 + k];
    if (part < 5) {
#pragma unroll
      for (int j = 0; j < 4; j++) {
        int ee = part * 4 + j;
        float a = f3b[ee];
        DOT40G(a, f3w, ee, d2);
        sc[p16 * 101 + 80 + ee] = fmaxf(a, 0.f);
      }
    }
    __syncthreads();
    if (act && part == 0) {
      float z = f4b[0];
      const float* dv = sc + p16 * 101 + 80;
      DOT20G(z, f4w, 0, dv);
      out[pos] = 1.f / (1.f + __expf(-z));
    }
  }
}

// ---------------------------------------------------------------------------
extern "C" void kernel_launch(void* const* d_in, const int* in_sizes, int n_in,
                              void* d_out, int out_size, void* d_ws,
                              size_t ws_size, hipStream_t stream) {
  const float* x    = (const float*)d_in[0];
  const float* cw   = (const float*)d_in[1];
  const float* Wv   = (const float*)d_in[2];
  const float* Wk   = (const float*)d_in[3];
  const float* Wq   = (const float*)d_in[4];
  const float* Wc   = (const float*)d_in[5];
  const float* bc   = (const float*)d_in[6];
  const float* lnAg = (const float*)d_in[7];
  const float* lnAb = (const float*)d_in[8];
  const float* W1   = (const float*)d_in[9];
  const float* b1   = (const float*)d_in[10];
  const float* W2   = (const float*)d_in[11];
  const float* b2   = (const float*)d_in[12];
  const float* lnBg = (const float*)d_in[13];
  const float* lnBb = (const float*)d_in[14];
  const float* f1w  = (const float*)d_in[15];
  const float* f1b  = (const float*)d_in[16];
  const float* f2w  = (const float*)d_in[17];
  const float* f2b  = (const float*)d_in[18];
  const float* f3w  = (const float*)d_in[19];
  const float* f3b  = (const float*)d_in[20];
  const float* f4w  = (const float*)d_in[21];
  const float* f4b  = (const float*)d_in[22];
  float* out = (float*)d_out;

  // ws floats: h 200000 | Mall 4*1800 | W2t 2400
  float* ws = (float*)d_ws;
  float* h = ws;
  float* Mall = ws + 200000;
  float* W2t = Mall + 4 * MLAYER;

  conv_pe_kernel<<<(B_ * L_ * E_ + 255) / 256, 256, 0, stream>>>(x, cw, h, Mall);

  for (int i = 0; i < 4; i++) {
    moment_kernel<<<B_ * H_ * NCH, 192, 0, stream>>>(
        h, Wk + i * 16, Wv + i * 16, W2 + i * 2400, W2t, Mall + i * MLAYER);
    dim3 grid((L_ + 15) / 16, B_);
    if (i < 3) {
      fused_kernel<0><<<grid, 128, 0, stream>>>(
          Mall + i * MLAYER, Wq + i * 16, Wc + i * 400, bc + i * 20,
          lnAg + i * 20, lnAb + i * 20, W1 + i * 2400, b1 + i * 120,
          W2t, b2 + i * 20, lnBg + i * 20, lnBb + i * 20, h,
          f1w, f1b, f2w, f2b, f3w, f3b, f4w, f4b, out);
    } else {
      fused_kernel<1><<<grid, 128, 0, stream>>>(
          Mall + i * MLAYER, Wq + i * 16, Wc + i * 400, bc + i * 20,
          lnAg + i * 20, lnAb + i * 20, W1 + i * 2400, b1 + i * 120,
          W2t, b2 + i * 20, lnBg + i * 20, lnBb + i * 20, h,
          f1w, f1b, f2w, f2b, f3w, f3b, f4w, f4b, out);
    }
  }
}